// Round 13
// baseline (1142.537 us; speedup 1.0000x reference)
//
#include <hip/hip_runtime.h>
#include <hip/hip_bf16.h>
#include <math.h>

// Problem constants
#define B_SZ 1024
#define T_SZ 512
#define CTX_N 23
#define D 320
#define L_LAYERS 5
#define H 8
#define FF 1280
#define NM1 49      // NMODES + 1
#define S 24        // CTX + 1
#define DH 40       // D / H
#define M_ROWS (B_SZ * S)   // 24576

typedef unsigned short ushort_t;
typedef __attribute__((ext_vector_type(8))) short bfrag8;   // 8 bf16 (4 VGPRs)
typedef __attribute__((ext_vector_type(4))) float facc4;    // 4 fp32 acc

__device__ __forceinline__ float wave_sum(float v) {
#pragma unroll
  for (int off = 32; off > 0; off >>= 1) v += __shfl_xor(v, off, 64);
  return v;
}

// tanh-form gelu (max |err| ~3e-4 << bf16 quantum, safe at +-inf)
__device__ __forceinline__ float gelu_fast(float x) {
  float t = __builtin_amdgcn_exp2f(x * (2.30211416f + 0.10294404f * x * x));
  return x - x * __builtin_amdgcn_rcpf(t + 1.0f);
}

__device__ __forceinline__ ushort_t f2b(float x) {
  __hip_bfloat16 h = __float2bfloat16(x);
  return *reinterpret_cast<ushort_t*>(&h);
}

__device__ __forceinline__ float b2f(ushort_t u) {
  __hip_bfloat16 h = *reinterpret_cast<__hip_bfloat16*>(&u);
  return __bfloat162float(h);
}

#define GLOAD_LDS16(g, l)                                     \
  __builtin_amdgcn_global_load_lds(                           \
      (const __attribute__((address_space(1))) void*)(g),     \
      (__attribute__((address_space(3))) void*)(l), 16, 0, 0)

// ---------------- all-weights f32 -> bf16 (dst regions contiguous) -----------
__global__ __launch_bounds__(256) void conv_all(
    const float* __restrict__ w_in, const float* __restrict__ w_out,
    const float* __restrict__ w1, const float* __restrict__ w2,
    const float* __restrict__ wh1, ushort_t* __restrict__ dst) {
  int i = blockIdx.x * 256 + threadIdx.x;
  const float* src;
  int off;
  if (i < 384000)       { src = w_in;  off = i; }
  else if (i < 512000)  { src = w_out; off = i - 384000; }
  else if (i < 1024000) { src = w1;    off = i - 512000; }
  else if (i < 1536000) { src = w2;    off = i - 1024000; }
  else                  { src = wh1;   off = i - 1536000; }
  float4 v = ((const float4*)src)[off];
  ushort4 o;
  o.x = f2b(v.x); o.y = f2b(v.y); o.z = f2b(v.z); o.w = f2b(v.w);
  ((ushort4*)dst)[i] = o;
}

// ---------------- embed ------------------------------------------------------
__global__ __launch_bounds__(256) void embed_kernel(
    const float* __restrict__ ctx, const float* __restrict__ W_e,
    const float* __restrict__ b_e, const float* __restrict__ cls,
    float* __restrict__ x) {
  int idx = blockIdx.x * 256 + threadIdx.x;
  int d = idx % D;
  int s = (idx / D) % S;
  int b = idx / (D * S);
  float v;
  if (s == 0)
    v = cls[d];
  else
    v = ctx[b * CTX_N + (s - 1)] * W_e[d] + b_e[d];
  x[idx] = v;
}

// ---------------- layernorm: fp32 in, bf16 out, one wave per row -------------
__global__ __launch_bounds__(256) void ln_kernel(
    const float* __restrict__ X, const float* __restrict__ w,
    const float* __restrict__ b, ushort_t* __restrict__ Y,
    int inStride, int outStride) {
  int wv = threadIdx.x >> 6;
  int lane = threadIdx.x & 63;
  int row = blockIdx.x * 4 + wv;
  const float* xr = X + (size_t)row * inStride;
  float v[5];
#pragma unroll
  for (int i = 0; i < 5; i++) v[i] = xr[lane + 64 * i];
  float s = v[0] + v[1] + v[2] + v[3] + v[4];
  s = wave_sum(s);
  float m = s * (1.0f / (float)D);
  float sq = 0.f;
#pragma unroll
  for (int i = 0; i < 5; i++) { float d0 = v[i] - m; sq += d0 * d0; }
  sq = wave_sum(sq);
  float inv = 1.0f / sqrtf(sq * (1.0f / (float)D) + 1e-5f);
  ushort_t* yr = Y + (size_t)row * outStride;
#pragma unroll
  for (int i = 0; i < 5; i++) {
    int d = lane + 64 * i;
    yr[d] = f2b((v[i] - m) * inv * w[d] + b[d]);
  }
}

// ---------------- bf16 MFMA GEMM (R5/R10 core), BK templated -----------------
// BM=64, BN=32*NT, 256 threads = 4 waves (2x2), wave tile 32 x 16*NT.
// Swizzle (bank-exact):
//  BKT=64: row stride 32 words (full bank wrap) -> key = laneM&7 over 8
//          chunk windows; 2 lanes/window/quarter -> conflict-free (R5-R10: 0).
//  BKT=32: row stride 16 words (half wrap): row parity supplies the 16-bank
//          split, key = (laneM>>1)&3 spreads pairs over the 4 chunk windows
//          -> 2 lanes/window/quarter -> conflict-free. (R12's key=0 was a
//          measured 4-way conflict: 3.4M SQ_LDS_BANK_CONFLICT.)
// Staging slot for row r chunk c: c ^ key(r), matching the frag-read key.
// Swapped MFMA operands -> D[n][m]: lane holds 4 consecutive n at fixed m.
// EPI: 1=bias+gelu->bf16, 2=bias+residual->f32, 3=bias+gelu->f32, 4=bias->bf16
template <int EPI, int NT, int BKT>
__global__ __launch_bounds__(256, 3) void gemm_mfma(
    const ushort_t* __restrict__ A, const ushort_t* __restrict__ W,
    const float* __restrict__ bias, const float* __restrict__ R,
    float* __restrict__ C, ushort_t* __restrict__ Cb, int M, int N, int K) {
  constexpr int BM_ = 64;
  constexpr int BN = 32 * NT;
  constexpr int MT = 2;
  constexpr int CH = BKT / 8;              // 16B chunks per row (8 or 4)
  constexpr int CM = CH - 1;
  constexpr int KC = BKT / 32;             // inner kc steps
  constexpr int ACH = BM_ * CH;            // A chunk count
  constexpr int WCH = BN * CH;             // W chunk count
  constexpr int ARND = (ACH + 255) / 256;
  constexpr int WRND = (WCH + 255) / 256;
  __shared__ __align__(16) ushort_t As[BM_ * BKT];
  __shared__ __align__(16) ushort_t Ws[BN * BKT];

  int tid = threadIdx.x;
  int lane = tid & 63;
  int wv = tid >> 6;
  int wvM = wv & 1, wvN = wv >> 1;
  int laneM = lane & 15;
  int kgrp = lane >> 4;
  int sKey = (BKT == 64) ? (laneM & 7) : ((laneM >> 1) & 3);
  int m0 = blockIdx.x * BM_;
  int n0 = blockIdx.y * BN;

  facc4 acc[MT][NT];
#pragma unroll
  for (int mt = 0; mt < MT; mt++)
#pragma unroll
    for (int nt = 0; nt < NT; nt++) acc[mt][nt] = (facc4){0.f, 0.f, 0.f, 0.f};

  for (int k0 = 0; k0 < K; k0 += BKT) {
#pragma unroll
    for (int r = 0; r < ARND; r++) {
      int c = r * 256 + tid;
      if (ACH % 256 == 0 || c < ACH) {
        int sr = c / CH, sl = c % CH;
        int swz = (BKT == 64) ? (sr & 7) : ((sr >> 1) & 3);
        int jgc = sl ^ swz;
        GLOAD_LDS16(A + (size_t)(m0 + sr) * K + k0 + jgc * 8, As + c * 8);
      }
    }
#pragma unroll
    for (int r = 0; r < WRND; r++) {
      int c = r * 256 + tid;
      if (WCH % 256 == 0 || c < WCH) {
        int sr = c / CH, sl = c % CH;
        int swz = (BKT == 64) ? (sr & 7) : ((sr >> 1) & 3);
        int jgc = sl ^ swz;
        GLOAD_LDS16(W + (size_t)(n0 + sr) * K + k0 + jgc * 8, Ws + c * 8);
      }
    }
    __syncthreads();   // drains vmcnt (global_load_lds) + orders LDS use
#pragma unroll
    for (int kc = 0; kc < KC; kc++) {
      int chunk = kc * 4 + kgrp;
      int jcol = ((chunk ^ sKey) & CM) * 8;
      bfrag8 af[MT];
#pragma unroll
      for (int mt = 0; mt < MT; mt++) {
        int row = wvM * 32 + mt * 16 + laneM;
        af[mt] = *(const bfrag8*)&As[row * BKT + jcol];
      }
      bfrag8 bf[NT];
#pragma unroll
      for (int nt = 0; nt < NT; nt++) {
        int nrow = wvN * (BN / 2) + nt * 16 + laneM;
        bf[nt] = *(const bfrag8*)&Ws[nrow * BKT + jcol];
      }
#pragma unroll
      for (int mt = 0; mt < MT; mt++)
#pragma unroll
        for (int nt = 0; nt < NT; nt++)
          acc[mt][nt] = __builtin_amdgcn_mfma_f32_16x16x32_bf16(
              bf[nt], af[mt], acc[mt][nt], 0, 0, 0);   // swapped: D[n][m]
    }
    __syncthreads();   // protect LDS from next iteration's staging
  }

  // epilogue (transposed D): m = laneM-based, n = kgrp*4 + reg (consecutive)
#pragma unroll
  for (int mt = 0; mt < MT; mt++) {
    int m = m0 + wvM * 32 + mt * 16 + laneM;
#pragma unroll
    for (int nt = 0; nt < NT; nt++) {
      int n = n0 + wvN * (BN / 2) + nt * 16 + kgrp * 4;
      float4 bv = *(const float4*)(bias + n);
      facc4 a = acc[mt][nt];
      float v0 = a[0] + bv.x, v1 = a[1] + bv.y, v2 = a[2] + bv.z,
            v3 = a[3] + bv.w;
      size_t off = (size_t)m * N + n;
      if constexpr (EPI == 1) {
        ushort4 o;
        o.x = f2b(gelu_fast(v0)); o.y = f2b(gelu_fast(v1));
        o.z = f2b(gelu_fast(v2)); o.w = f2b(gelu_fast(v3));
        *(ushort4*)(Cb + off) = o;
      } else if constexpr (EPI == 2) {
        float4 r = *(const float4*)(R + off);
        float4 o = {v0 + r.x, v1 + r.y, v2 + r.z, v3 + r.w};
        *(float4*)(C + off) = o;
      } else if constexpr (EPI == 3) {
        float4 o = {gelu_fast(v0), gelu_fast(v1), gelu_fast(v2),
                    gelu_fast(v3)};
        *(float4*)(C + off) = o;
      } else {  // EPI == 4
        ushort4 o;
        o.x = f2b(v0); o.y = f2b(v1); o.z = f2b(v2); o.w = f2b(v3);
        *(ushort4*)(Cb + off) = o;
      }
    }
  }
}

// ---------------- attention v2: one block per (b,h), conflict-free LDS -------
__global__ __launch_bounds__(256) void attn_kernel(
    const ushort_t* __restrict__ qkv, ushort_t* __restrict__ o) {
  int b = blockIdx.x >> 3;
  int h = blockIdx.x & 7;
  __shared__ __align__(16) float q[S][44];
  __shared__ __align__(16) float v[S][44];
  __shared__ __align__(16) float kT[DH][28];
  __shared__ __align__(16) float sc[S][28];
  int tid = threadIdx.x;
  const ushort_t* base = qkv + (size_t)b * S * (3 * D) + h * DH;

  for (int idx = tid; idx < 720; idx += 256) {
    int t = idx / 240;          // 0=q 1=k 2=v
    int r = idx % 240;
    int s = r / 10, dg = r % 10;
    ushort4 u = *(const ushort4*)(base + (size_t)s * (3 * D) + t * D + dg * 4);
    float4 f = {b2f(u.x), b2f(u.y), b2f(u.z), b2f(u.w)};
    if (t == 0) {
      *(float4*)&q[s][dg * 4] = f;
    } else if (t == 2) {
      *(float4*)&v[s][dg * 4] = f;
    } else {
      kT[dg * 4 + 0][s] = f.x;
      kT[dg * 4 + 1][s] = f.y;
      kT[dg * 4 + 2][s] = f.z;
      kT[dg * 4 + 3][s] = f.w;
    }
  }
  __syncthreads();

  if (tid < 144) {
    int i = tid / 6, jg = tid % 6;
    facc4 acc = {0.f, 0.f, 0.f, 0.f};
#pragma unroll
    for (int d = 0; d < DH; d++) {
      float qv = q[i][d];
      float4 kv = *(const float4*)&kT[d][jg * 4];
      acc[0] += qv * kv.x; acc[1] += qv * kv.y;
      acc[2] += qv * kv.z; acc[3] += qv * kv.w;
    }
    const float sca = 0.15811388300841897f;  // 1/sqrt(40)
    float4 ov = {acc[0] * sca, acc[1] * sca, acc[2] * sca, acc[3] * sca};
    *(float4*)&sc[i][jg * 4] = ov;
  }
  __syncthreads();

  if (tid < S) {
    float mx = -1e30f;
#pragma unroll
    for (int j = 0; j < S; j++) mx = fmaxf(mx, sc[tid][j]);
    float sum = 0.f;
#pragma unroll
    for (int j = 0; j < S; j++) {
      float e = __expf(sc[tid][j] - mx);
      sc[tid][j] = e;
      sum += e;
    }
    float rr = 1.0f / sum;
#pragma unroll
    for (int j = 0; j < S; j++) sc[tid][j] *= rr;
  }
  __syncthreads();

  if (tid < 240) {
    int i = tid / 10, dg = tid % 10;
    facc4 acc = {0.f, 0.f, 0.f, 0.f};
#pragma unroll
    for (int j = 0; j < S; j++) {
      float p = sc[i][j];
      float4 vv = *(const float4*)&v[j][dg * 4];
      acc[0] += p * vv.x; acc[1] += p * vv.y;
      acc[2] += p * vv.z; acc[3] += p * vv.w;
    }
    ushort4 ov;
    ov.x = f2b(acc[0]); ov.y = f2b(acc[1]);
    ov.z = f2b(acc[2]); ov.w = f2b(acc[3]);
    *(ushort4*)(o + (size_t)b * S * D + (size_t)i * D + h * DH + dg * 4) = ov;
  }
}

// ---------------- head tail: c = g@Wh2^T+bh2 ; cheb ; sigmoid ----------------
__global__ __launch_bounds__(256) void head_cheb(
    const float* __restrict__ g, const float* __restrict__ Wh2,
    const float* __restrict__ bh2, const float* __restrict__ k_norm,
    float* __restrict__ out) {
  int b = blockIdx.x;
  __shared__ float gs[D];
  __shared__ float cs[NM1];
  int tid = threadIdx.x;
  for (int i = tid; i < D; i += 256) gs[i] = g[(size_t)b * D + i];
  __syncthreads();
  if (tid < NM1) {
    const float* wr = Wh2 + (size_t)tid * D;
    float s = bh2[tid];
    for (int d = 0; d < D; d++) s += gs[d] * wr[d];
    cs[tid] = s;
  }
  __syncthreads();
  for (int t = tid; t < T_SZ; t += 256) {
    float xv = k_norm[(size_t)b * T_SZ + t];
    float tp = 1.f, tc = xv;
    float acc = cs[0] + cs[1] * xv;
#pragma unroll
    for (int n = 2; n < NM1; n++) {
      float tn = 2.f * xv * tc - tp;
      acc += cs[n] * tn;
      tp = tc;
      tc = tn;
    }
    out[(size_t)b * T_SZ + t] = 1.f / (1.f + expf(-acc));
  }
}

extern "C" void kernel_launch(void* const* d_in, const int* in_sizes, int n_in,
                              void* d_out, int out_size, void* d_ws,
                              size_t ws_size, hipStream_t stream) {
  const float* k_norm = (const float*)d_in[0];
  const float* ctx    = (const float*)d_in[1];
  const float* W_e    = (const float*)d_in[2];
  const float* b_e    = (const float*)d_in[3];
  const float* cls    = (const float*)d_in[4];
  const float* ln1_w  = (const float*)d_in[5];
  const float* ln1_b  = (const float*)d_in[6];
  const float* W_in   = (const float*)d_in[7];
  const float* b_in   = (const float*)d_in[8];
  const float* W_out  = (const float*)d_in[9];
  const float* b_out  = (const float*)d_in[10];
  const float* ln2_w  = (const float*)d_in[11];
  const float* ln2_b  = (const float*)d_in[12];
  const float* W1     = (const float*)d_in[13];
  const float* b1     = (const float*)d_in[14];
  const float* W2     = (const float*)d_in[15];
  const float* b2     = (const float*)d_in[16];
  const float* hln_w  = (const float*)d_in[17];
  const float* hln_b  = (const float*)d_in[18];
  const float* Wh1    = (const float*)d_in[19];
  const float* bh1    = (const float*)d_in[20];
  const float* Wh2    = (const float*)d_in[21];
  const float* bh2    = (const float*)d_in[22];
  float* out = (float*)d_out;

  float* x = (float*)d_ws;
  ushort_t* hbuf = (ushort_t*)(x + (size_t)M_ROWS * D);
  ushort_t* big = hbuf + (size_t)M_ROWS * D;
  ushort_t* wb_in = big + (size_t)M_ROWS * FF;
  ushort_t* wb_out = wb_in + (size_t)L_LAYERS * 3 * D * D;
  ushort_t* wb1 = wb_out + (size_t)L_LAYERS * D * D;
  ushort_t* wb2 = wb1 + (size_t)L_LAYERS * FF * D;
  ushort_t* wbh1 = wb2 + (size_t)L_LAYERS * D * FF;
  ushort_t* hcls = wbh1 + (size_t)D * D;
  float* ghead = (float*)(hcls + (size_t)B_SZ * D);

  conv_all<<<6100, 256, 0, stream>>>(W_in, W_out, W1, W2, Wh1, wb_in);

  embed_kernel<<<(M_ROWS * D) / 256, 256, 0, stream>>>(ctx, W_e, b_e, cls, x);

  for (int l = 0; l < L_LAYERS; l++) {
    ln_kernel<<<M_ROWS / 4, 256, 0, stream>>>(x, ln1_w + l * D, ln1_b + l * D,
                                              hbuf, D, D);
    gemm_mfma<4, 5, 32><<<dim3(M_ROWS / 64, (3 * D) / 160), 256, 0, stream>>>(
        hbuf, wb_in + (size_t)l * 3 * D * D, b_in + (size_t)l * 3 * D, nullptr,
        nullptr, big, M_ROWS, 3 * D, D);
    attn_kernel<<<B_SZ * H, 256, 0, stream>>>(big, hbuf);
    gemm_mfma<2, 5, 32><<<dim3(M_ROWS / 64, D / 160), 256, 0, stream>>>(
        hbuf, wb_out + (size_t)l * D * D, b_out + (size_t)l * D, x, x, nullptr,
        M_ROWS, D, D);
    ln_kernel<<<M_ROWS / 4, 256, 0, stream>>>(x, ln2_w + l * D, ln2_b + l * D,
                                              hbuf, D, D);
    gemm_mfma<1, 5, 32><<<dim3(M_ROWS / 64, FF / 160), 256, 0, stream>>>(
        hbuf, wb1 + (size_t)l * FF * D, b1 + (size_t)l * FF, nullptr, nullptr,
        big, M_ROWS, FF, D);
    // ffn2: K=1280 -> keep BK=64 (20 iters; BK=32 would double barrier count)
    gemm_mfma<2, 5, 64><<<dim3(M_ROWS / 64, D / 160), 256, 0, stream>>>(
        big, wb2 + (size_t)l * D * FF, b2 + (size_t)l * D, x, x, nullptr,
        M_ROWS, D, FF);
  }

  ln_kernel<<<B_SZ / 4, 256, 0, stream>>>(x, hln_w, hln_b, hcls, S * D, D);
  gemm_mfma<3, 5, 32><<<dim3(B_SZ / 64, D / 160), 256, 0, stream>>>(
      hcls, wbh1, bh1, nullptr, ghead, nullptr, B_SZ, D, D);
  head_cheb<<<B_SZ, 256, 0, stream>>>(ghead, Wh2, bh2, k_norm, out);
}

// Round 14
// 988.089 us; speedup vs baseline: 1.1563x; 1.1563x over previous
//
#include <hip/hip_runtime.h>
#include <hip/hip_bf16.h>
#include <math.h>

// Problem constants
#define B_SZ 1024
#define T_SZ 512
#define CTX_N 23
#define D 320
#define L_LAYERS 5
#define H 8
#define FF 1280
#define NM1 49      // NMODES + 1
#define S 24        // CTX + 1
#define DH 40       // D / H
#define M_ROWS (B_SZ * S)   // 24576

typedef unsigned short ushort_t;
typedef __attribute__((ext_vector_type(8))) short bfrag8;   // 8 bf16 (4 VGPRs)
typedef __attribute__((ext_vector_type(4))) float facc4;    // 4 fp32 acc

__device__ __forceinline__ float wave_sum(float v) {
#pragma unroll
  for (int off = 32; off > 0; off >>= 1) v += __shfl_xor(v, off, 64);
  return v;
}

// tanh-form gelu (max |err| ~3e-4 << bf16 quantum, safe at +-inf)
__device__ __forceinline__ float gelu_fast(float x) {
  float t = __builtin_amdgcn_exp2f(x * (2.30211416f + 0.10294404f * x * x));
  return x - x * __builtin_amdgcn_rcpf(t + 1.0f);
}

__device__ __forceinline__ ushort_t f2b(float x) {
  __hip_bfloat16 h = __float2bfloat16(x);
  return *reinterpret_cast<ushort_t*>(&h);
}

__device__ __forceinline__ float b2f(ushort_t u) {
  __hip_bfloat16 h = *reinterpret_cast<__hip_bfloat16*>(&u);
  return __bfloat162float(h);
}

#define GLOAD_LDS16(g, l)                                     \
  __builtin_amdgcn_global_load_lds(                           \
      (const __attribute__((address_space(1))) void*)(g),     \
      (__attribute__((address_space(3))) void*)(l), 16, 0, 0)

// ---------------- all-weights f32 -> bf16 (dst regions contiguous) -----------
__global__ __launch_bounds__(256) void conv_all(
    const float* __restrict__ w_in, const float* __restrict__ w_out,
    const float* __restrict__ w1, const float* __restrict__ w2,
    const float* __restrict__ wh1, ushort_t* __restrict__ dst) {
  int i = blockIdx.x * 256 + threadIdx.x;
  const float* src;
  int off;
  if (i < 384000)       { src = w_in;  off = i; }
  else if (i < 512000)  { src = w_out; off = i - 384000; }
  else if (i < 1024000) { src = w1;    off = i - 512000; }
  else if (i < 1536000) { src = w2;    off = i - 1024000; }
  else                  { src = wh1;   off = i - 1536000; }
  float4 v = ((const float4*)src)[off];
  ushort4 o;
  o.x = f2b(v.x); o.y = f2b(v.y); o.z = f2b(v.z); o.w = f2b(v.w);
  ((ushort4*)dst)[i] = o;
}

// ---------------- embed ------------------------------------------------------
__global__ __launch_bounds__(256) void embed_kernel(
    const float* __restrict__ ctx, const float* __restrict__ W_e,
    const float* __restrict__ b_e, const float* __restrict__ cls,
    float* __restrict__ x) {
  int idx = blockIdx.x * 256 + threadIdx.x;
  int d = idx % D;
  int s = (idx / D) % S;
  int b = idx / (D * S);
  float v;
  if (s == 0)
    v = cls[d];
  else
    v = ctx[b * CTX_N + (s - 1)] * W_e[d] + b_e[d];
  x[idx] = v;
}

// ---------------- layernorm: fp32 in, bf16 out, one wave per row -------------
__global__ __launch_bounds__(256) void ln_kernel(
    const float* __restrict__ X, const float* __restrict__ w,
    const float* __restrict__ b, ushort_t* __restrict__ Y,
    int inStride, int outStride) {
  int wv = threadIdx.x >> 6;
  int lane = threadIdx.x & 63;
  int row = blockIdx.x * 4 + wv;
  const float* xr = X + (size_t)row * inStride;
  float v[5];
#pragma unroll
  for (int i = 0; i < 5; i++) v[i] = xr[lane + 64 * i];
  float s = v[0] + v[1] + v[2] + v[3] + v[4];
  s = wave_sum(s);
  float m = s * (1.0f / (float)D);
  float sq = 0.f;
#pragma unroll
  for (int i = 0; i < 5; i++) { float d0 = v[i] - m; sq += d0 * d0; }
  sq = wave_sum(sq);
  float inv = 1.0f / sqrtf(sq * (1.0f / (float)D) + 1e-5f);
  ushort_t* yr = Y + (size_t)row * outStride;
#pragma unroll
  for (int i = 0; i < 5; i++) {
    int d = lane + 64 * i;
    yr[d] = f2b((v[i] - m) * inv * w[d] + b[d]);
  }
}

// ---------------- bf16 MFMA GEMM (R10 config — measured optimum) -------------
// BM=64, BK=64, BN=32*NT (NT=5 -> 160), 256 threads = 4 waves (2x2),
// wave tile 32 x 80. Single-buffer LDS, 2 barriers/iter, swizzled
// K-contiguous layout (chunk j of row r at slot j^(r&7)): conflict-free
// (R5-R10 measured 0). 28KB LDS -> 5 blocks/CU.
// Tile-space ledger (this session): BK=128-equiv dbuf (R6) loses to
// occupancy; BK=32 (R12/R13) loses to barrier count even conflict-free;
// BM=128 loses to grid size; LDS-free (R7) loses to coalescing/reuse.
// Swapped MFMA operands -> D[n][m]: lane holds 4 consecutive n at fixed m.
// EPI: 1=bias+gelu->bf16, 2=bias+residual->f32, 3=bias+gelu->f32, 4=bias->bf16
template <int EPI, int NT>
__global__ __launch_bounds__(256, 3) void gemm_mfma(
    const ushort_t* __restrict__ A, const ushort_t* __restrict__ W,
    const float* __restrict__ bias, const float* __restrict__ R,
    float* __restrict__ C, ushort_t* __restrict__ Cb, int M, int N, int K) {
  constexpr int BM_ = 64, BK = 64;
  constexpr int BN = 32 * NT;
  constexpr int MT = 2;
  constexpr int AR = 2;          // A staging rounds (32 rows each)
  constexpr int WR = BN / 32;    // W staging rounds
  __shared__ __align__(16) ushort_t As[BM_ * BK];
  __shared__ __align__(16) ushort_t Ws[BN * BK];

  int tid = threadIdx.x;
  int lane = tid & 63;
  int wv = tid >> 6;
  int wvM = wv & 1, wvN = wv >> 1;
  int laneM = lane & 15;
  int kgrp = lane >> 4;
  int sA = laneM & 7;
  int m0 = blockIdx.x * BM_;
  int n0 = blockIdx.y * BN;

  facc4 acc[MT][NT];
#pragma unroll
  for (int mt = 0; mt < MT; mt++)
#pragma unroll
    for (int nt = 0; nt < NT; nt++) acc[mt][nt] = (facc4){0.f, 0.f, 0.f, 0.f};

  int srow = tid >> 3;
  int jg = (tid & 7) ^ (srow & 7);
  const ushort_t* Ag = A + (size_t)(m0 + srow) * K + jg * 8;
  const ushort_t* Wg = W + (size_t)(n0 + srow) * K + jg * 8;

  for (int k0 = 0; k0 < K; k0 += BK) {
#pragma unroll
    for (int r = 0; r < AR; r++)
      GLOAD_LDS16(Ag + (size_t)r * 32 * K + k0, As + r * 2048 + tid * 8);
#pragma unroll
    for (int r = 0; r < WR; r++)
      GLOAD_LDS16(Wg + (size_t)r * 32 * K + k0, Ws + r * 2048 + tid * 8);
    __syncthreads();   // drains vmcnt (global_load_lds) + orders LDS use
#pragma unroll
    for (int kc = 0; kc < 2; kc++) {
      int jcol = ((kc * 4 + kgrp) ^ sA) * 8;
      bfrag8 af[MT];
#pragma unroll
      for (int mt = 0; mt < MT; mt++) {
        int row = wvM * 32 + mt * 16 + laneM;
        af[mt] = *(const bfrag8*)&As[row * 64 + jcol];
      }
      bfrag8 bf[NT];
#pragma unroll
      for (int nt = 0; nt < NT; nt++) {
        int nrow = wvN * (BN / 2) + nt * 16 + laneM;
        bf[nt] = *(const bfrag8*)&Ws[nrow * 64 + jcol];
      }
#pragma unroll
      for (int mt = 0; mt < MT; mt++)
#pragma unroll
        for (int nt = 0; nt < NT; nt++)
          acc[mt][nt] = __builtin_amdgcn_mfma_f32_16x16x32_bf16(
              bf[nt], af[mt], acc[mt][nt], 0, 0, 0);   // swapped: D[n][m]
    }
    __syncthreads();   // protect LDS from next iteration's staging
  }

  // epilogue (transposed D): m = laneM-based, n = kgrp*4 + reg (consecutive)
#pragma unroll
  for (int mt = 0; mt < MT; mt++) {
    int m = m0 + wvM * 32 + mt * 16 + laneM;
#pragma unroll
    for (int nt = 0; nt < NT; nt++) {
      int n = n0 + wvN * (BN / 2) + nt * 16 + kgrp * 4;
      float4 bv = *(const float4*)(bias + n);
      facc4 a = acc[mt][nt];
      float v0 = a[0] + bv.x, v1 = a[1] + bv.y, v2 = a[2] + bv.z,
            v3 = a[3] + bv.w;
      size_t off = (size_t)m * N + n;
      if constexpr (EPI == 1) {
        ushort4 o;
        o.x = f2b(gelu_fast(v0)); o.y = f2b(gelu_fast(v1));
        o.z = f2b(gelu_fast(v2)); o.w = f2b(gelu_fast(v3));
        *(ushort4*)(Cb + off) = o;
      } else if constexpr (EPI == 2) {
        float4 r = *(const float4*)(R + off);
        float4 o = {v0 + r.x, v1 + r.y, v2 + r.z, v3 + r.w};
        *(float4*)(C + off) = o;
      } else if constexpr (EPI == 3) {
        float4 o = {gelu_fast(v0), gelu_fast(v1), gelu_fast(v2),
                    gelu_fast(v3)};
        *(float4*)(C + off) = o;
      } else {  // EPI == 4
        ushort4 o;
        o.x = f2b(v0); o.y = f2b(v1); o.z = f2b(v2); o.w = f2b(v3);
        *(ushort4*)(Cb + off) = o;
      }
    }
  }
}

// ---------------- attention v2: one block per (b,h), conflict-free LDS -------
__global__ __launch_bounds__(256) void attn_kernel(
    const ushort_t* __restrict__ qkv, ushort_t* __restrict__ o) {
  int b = blockIdx.x >> 3;
  int h = blockIdx.x & 7;
  __shared__ __align__(16) float q[S][44];
  __shared__ __align__(16) float v[S][44];
  __shared__ __align__(16) float kT[DH][28];
  __shared__ __align__(16) float sc[S][28];
  int tid = threadIdx.x;
  const ushort_t* base = qkv + (size_t)b * S * (3 * D) + h * DH;

  for (int idx = tid; idx < 720; idx += 256) {
    int t = idx / 240;          // 0=q 1=k 2=v
    int r = idx % 240;
    int s = r / 10, dg = r % 10;
    ushort4 u = *(const ushort4*)(base + (size_t)s * (3 * D) + t * D + dg * 4);
    float4 f = {b2f(u.x), b2f(u.y), b2f(u.z), b2f(u.w)};
    if (t == 0) {
      *(float4*)&q[s][dg * 4] = f;
    } else if (t == 2) {
      *(float4*)&v[s][dg * 4] = f;
    } else {
      kT[dg * 4 + 0][s] = f.x;
      kT[dg * 4 + 1][s] = f.y;
      kT[dg * 4 + 2][s] = f.z;
      kT[dg * 4 + 3][s] = f.w;
    }
  }
  __syncthreads();

  if (tid < 144) {
    int i = tid / 6, jg = tid % 6;
    facc4 acc = {0.f, 0.f, 0.f, 0.f};
#pragma unroll
    for (int d = 0; d < DH; d++) {
      float qv = q[i][d];
      float4 kv = *(const float4*)&kT[d][jg * 4];
      acc[0] += qv * kv.x; acc[1] += qv * kv.y;
      acc[2] += qv * kv.z; acc[3] += qv * kv.w;
    }
    const float sca = 0.15811388300841897f;  // 1/sqrt(40)
    float4 ov = {acc[0] * sca, acc[1] * sca, acc[2] * sca, acc[3] * sca};
    *(float4*)&sc[i][jg * 4] = ov;
  }
  __syncthreads();

  if (tid < S) {
    float mx = -1e30f;
#pragma unroll
    for (int j = 0; j < S; j++) mx = fmaxf(mx, sc[tid][j]);
    float sum = 0.f;
#pragma unroll
    for (int j = 0; j < S; j++) {
      float e = __expf(sc[tid][j] - mx);
      sc[tid][j] = e;
      sum += e;
    }
    float rr = 1.0f / sum;
#pragma unroll
    for (int j = 0; j < S; j++) sc[tid][j] *= rr;
  }
  __syncthreads();

  if (tid < 240) {
    int i = tid / 10, dg = tid % 10;
    facc4 acc = {0.f, 0.f, 0.f, 0.f};
#pragma unroll
    for (int j = 0; j < S; j++) {
      float p = sc[i][j];
      float4 vv = *(const float4*)&v[j][dg * 4];
      acc[0] += p * vv.x; acc[1] += p * vv.y;
      acc[2] += p * vv.z; acc[3] += p * vv.w;
    }
    ushort4 ov;
    ov.x = f2b(acc[0]); ov.y = f2b(acc[1]);
    ov.z = f2b(acc[2]); ov.w = f2b(acc[3]);
    *(ushort4*)(o + (size_t)b * S * D + (size_t)i * D + h * DH + dg * 4) = ov;
  }
}

// ---------------- head tail: c = g@Wh2^T+bh2 ; cheb ; sigmoid ----------------
__global__ __launch_bounds__(256) void head_cheb(
    const float* __restrict__ g, const float* __restrict__ Wh2,
    const float* __restrict__ bh2, const float* __restrict__ k_norm,
    float* __restrict__ out) {
  int b = blockIdx.x;
  __shared__ float gs[D];
  __shared__ float cs[NM1];
  int tid = threadIdx.x;
  for (int i = tid; i < D; i += 256) gs[i] = g[(size_t)b * D + i];
  __syncthreads();
  if (tid < NM1) {
    const float* wr = Wh2 + (size_t)tid * D;
    float s = bh2[tid];
    for (int d = 0; d < D; d++) s += gs[d] * wr[d];
    cs[tid] = s;
  }
  __syncthreads();
  for (int t = tid; t < T_SZ; t += 256) {
    float xv = k_norm[(size_t)b * T_SZ + t];
    float tp = 1.f, tc = xv;
    float acc = cs[0] + cs[1] * xv;
#pragma unroll
    for (int n = 2; n < NM1; n++) {
      float tn = 2.f * xv * tc - tp;
      acc += cs[n] * tn;
      tp = tc;
      tc = tn;
    }
    out[(size_t)b * T_SZ + t] = 1.f / (1.f + expf(-acc));
  }
}

extern "C" void kernel_launch(void* const* d_in, const int* in_sizes, int n_in,
                              void* d_out, int out_size, void* d_ws,
                              size_t ws_size, hipStream_t stream) {
  const float* k_norm = (const float*)d_in[0];
  const float* ctx    = (const float*)d_in[1];
  const float* W_e    = (const float*)d_in[2];
  const float* b_e    = (const float*)d_in[3];
  const float* cls    = (const float*)d_in[4];
  const float* ln1_w  = (const float*)d_in[5];
  const float* ln1_b  = (const float*)d_in[6];
  const float* W_in   = (const float*)d_in[7];
  const float* b_in   = (const float*)d_in[8];
  const float* W_out  = (const float*)d_in[9];
  const float* b_out  = (const float*)d_in[10];
  const float* ln2_w  = (const float*)d_in[11];
  const float* ln2_b  = (const float*)d_in[12];
  const float* W1     = (const float*)d_in[13];
  const float* b1     = (const float*)d_in[14];
  const float* W2     = (const float*)d_in[15];
  const float* b2     = (const float*)d_in[16];
  const float* hln_w  = (const float*)d_in[17];
  const float* hln_b  = (const float*)d_in[18];
  const float* Wh1    = (const float*)d_in[19];
  const float* bh1    = (const float*)d_in[20];
  const float* Wh2    = (const float*)d_in[21];
  const float* bh2    = (const float*)d_in[22];
  float* out = (float*)d_out;

  float* x = (float*)d_ws;
  ushort_t* hbuf = (ushort_t*)(x + (size_t)M_ROWS * D);
  ushort_t* big = hbuf + (size_t)M_ROWS * D;
  ushort_t* wb_in = big + (size_t)M_ROWS * FF;
  ushort_t* wb_out = wb_in + (size_t)L_LAYERS * 3 * D * D;
  ushort_t* wb1 = wb_out + (size_t)L_LAYERS * D * D;
  ushort_t* wb2 = wb1 + (size_t)L_LAYERS * FF * D;
  ushort_t* wbh1 = wb2 + (size_t)L_LAYERS * D * FF;
  ushort_t* hcls = wbh1 + (size_t)D * D;
  float* ghead = (float*)(hcls + (size_t)B_SZ * D);

  conv_all<<<6100, 256, 0, stream>>>(W_in, W_out, W1, W2, Wh1, wb_in);

  embed_kernel<<<(M_ROWS * D) / 256, 256, 0, stream>>>(ctx, W_e, b_e, cls, x);

  for (int l = 0; l < L_LAYERS; l++) {
    ln_kernel<<<M_ROWS / 4, 256, 0, stream>>>(x, ln1_w + l * D, ln1_b + l * D,
                                              hbuf, D, D);
    gemm_mfma<4, 5><<<dim3(M_ROWS / 64, (3 * D) / 160), 256, 0, stream>>>(
        hbuf, wb_in + (size_t)l * 3 * D * D, b_in + (size_t)l * 3 * D, nullptr,
        nullptr, big, M_ROWS, 3 * D, D);
    attn_kernel<<<B_SZ * H, 256, 0, stream>>>(big, hbuf);
    gemm_mfma<2, 5><<<dim3(M_ROWS / 64, D / 160), 256, 0, stream>>>(
        hbuf, wb_out + (size_t)l * D * D, b_out + (size_t)l * D, x, x, nullptr,
        M_ROWS, D, D);
    ln_kernel<<<M_ROWS / 4, 256, 0, stream>>>(x, ln2_w + l * D, ln2_b + l * D,
                                              hbuf, D, D);
    gemm_mfma<1, 5><<<dim3(M_ROWS / 64, FF / 160), 256, 0, stream>>>(
        hbuf, wb1 + (size_t)l * FF * D, b1 + (size_t)l * FF, nullptr, nullptr,
        big, M_ROWS, FF, D);
    gemm_mfma<2, 5><<<dim3(M_ROWS / 64, D / 160), 256, 0, stream>>>(
        big, wb2 + (size_t)l * D * FF, b2 + (size_t)l * D, x, x, nullptr,
        M_ROWS, D, FF);
  }

  ln_kernel<<<B_SZ / 4, 256, 0, stream>>>(x, hln_w, hln_b, hcls, S * D, D);
  gemm_mfma<3, 5><<<dim3(B_SZ / 64, D / 160), 256, 0, stream>>>(
      hcls, wbh1, bh1, nullptr, ghead, nullptr, B_SZ, D, D);
  head_cheb<<<B_SZ, 256, 0, stream>>>(ghead, Wh2, bh2, k_norm, out);
}